// Round 8
// baseline (3101.703 us; speedup 1.0000x reference)
//
#include <hip/hip_runtime.h>
#include <math.h>

// ConvGRU v7: ONE persistent cooperative kernel, neighbor-flag pipeline.
// x: (4,16,64,64,64) f32, Wx: (96,16,3,3), bx: (96), Wh: (96,32,3,3).
// r-gate dead -> M = 32 oc x 2 gates; K = 48 cin x 12 (9 taps + 3 phantoms)
// = 576 = 36 MFMA chunks of 16 (chunks 0-11 = x cins, 12-35 = h cins).
// Block (b,y) = 4 waves, owns image row y for all 64 steps. Per step:
//   stage x(t) -> 12 x-chunks GEMM -> spin on prog[b][y+-1] >= t ->
//   fence -> stage h^t rows -> 24 h-chunks -> epilogue h^{t+1} -> fence ->
//   publish prog[b][y] = t+1 (device-scope release).
// prog poisoned 0xAA... = negative (signed) -> consumers just keep spinning
// until first real publish; t=0 waits on nothing (h^0 = memset zeros).
// h ping-pongs d_out <-> d_ws; t=63 (odd) writes d_out.

typedef _Float16 half8 __attribute__((ext_vector_type(8)));
typedef float floatx16 __attribute__((ext_vector_type(16)));

#define NROWS 144          // 48 cin * 3 ky
#define RSTRIDE 136        // bytes per LDS row: cols -2..65 as f16
#define LDS_DW ((NROWS * RSTRIDE + 16) / 4)

static __device__ __forceinline__ unsigned pack2(float a, float b) {
    _Float16 ha = (_Float16)a, hb = (_Float16)b;
    unsigned short ua = *(unsigned short*)&ha, ub = *(unsigned short*)&hb;
    return (unsigned)ua | ((unsigned)ub << 16);
}

// ---- pre-kernel: weights -> A-fragment layout (verified in R6) ----
__global__ __launch_bounds__(64) void build_wfrag(
    const float* __restrict__ Wx, const float* __restrict__ Wh,
    uint4* __restrict__ wfrag)
{
    const int bid   = blockIdx.x;            // 0..71
    const int mtile = bid / 36, chunk = bid % 36;
    const int lane  = threadIdx.x;
    const int m     = lane & 31;
    const int grow  = (m < 16) ? (mtile * 16 + m) : (64 + mtile * 16 + (m - 16));
    unsigned short h[8];
    for (int j = 0; j < 8; ++j) {
        int k   = chunk * 16 + (lane >> 5) * 8 + j;
        int cin = k / 12, t12 = k - cin * 12;
        int p = t12 >> 1, o = t12 & 1;
        int ky = p >> 1, q = p & 1;
        int kx = q ? (2 + o) : o;            // q=1,o=1 -> phantom (w=0)
        float w = 0.0f;
        if (!(q && o)) {
            if (cin < 16) w = Wx[((size_t)grow * 16 + cin) * 9 + ky * 3 + kx];
            else          w = Wh[((size_t)grow * 32 + (cin - 16)) * 9 + ky * 3 + kx];
        }
        _Float16 hw = (_Float16)w;
        h[j] = *(unsigned short*)&hw;
    }
    uint4 o4;
    o4.x = (unsigned)h[0] | ((unsigned)h[1] << 16);
    o4.y = (unsigned)h[2] | ((unsigned)h[3] << 16);
    o4.z = (unsigned)h[4] | ((unsigned)h[5] << 16);
    o4.w = (unsigned)h[6] | ((unsigned)h[7] << 16);
    wfrag[(size_t)bid * 64 + lane] = o4;
}

__global__ __launch_bounds__(256, 1) void convgru_persist(
    const float* __restrict__ x, const float* __restrict__ bx,
    const uint4* __restrict__ wfrag,
    float* __restrict__ hA,      // d_out: src of even t, dst of odd t
    float* __restrict__ hB,      // d_ws:  dst of even t, src of odd t
    int* __restrict__ prog)
{
    __shared__ unsigned int plds[LDS_DW];
    const int tx = threadIdx.x;
    const int y  = blockIdx.x;               // image row 0..63
    const int b  = blockIdx.y;               // batch 0..3

    // halo cols -2,-1 / 64,65 zeroed once (staging never writes them)
    if (tx < NROWS) { plds[tx * 34] = 0u; plds[tx * 34 + 33] = 0u; }

    const int lane  = tx & 63;
    const int wv    = tx >> 6;
    const int mtile = wv & 1;
    const int ntile = wv >> 1;
    const int xpx   = ntile * 32 + (lane & 31);
    const int half  = lane >> 5;
    const bool par  = (xpx & 1) != 0;
    const int basev = ((2 * xpx + 2) & ~3) + half * (2 * RSTRIDE);
    const char* lb  = (const char*)plds + basev;

    for (int t = 0; t < 64; ++t) {
        const float* hsrc = (t & 1) ? hB : hA;
        float*       hdst = (t & 1) ? hA : hB;

        // ---- stage x rows: cin 0..15 -> LDS rows 0..47 (768 quad-tasks) ----
        #pragma unroll
        for (int i = 0; i < 3; ++i) {
            int task = i * 256 + tx;
            int rr   = task >> 4;            // 0..47
            int qd   = task & 15;
            int cin  = rr / 3;
            int ky   = rr - cin * 3;
            int ys   = y + ky - 1;
            float4 v = make_float4(0.f, 0.f, 0.f, 0.f);
            if ((unsigned)ys < 64u)
                v = *(const float4*)(x + ((size_t)(b * 16 + cin) * 64 + t) * 4096
                                       + ys * 64 + qd * 4);
            plds[rr * 34 + 2 * qd + 1] = pack2(v.x, v.y);
            plds[rr * 34 + 2 * qd + 2] = pack2(v.z, v.w);
        }
        __syncthreads();

        floatx16 acc;
        #pragma unroll
        for (int i = 0; i < 16; ++i) acc[i] = 0.0f;

        // ---- x-only GEMM chunks (no h dependency; overlaps neighbor wait) ----
        #pragma unroll
        for (int c = 0; c < 12; ++c) {
            uint4 aw = wfrag[(size_t)((mtile * 36 + c) * 64 + lane)];
            const int B0 = c * 4 * RSTRIDE;
            unsigned d0 = *(const unsigned*)(lb + B0);
            unsigned d1 = *(const unsigned*)(lb + B0 + 4);
            unsigned d2 = *(const unsigned*)(lb + B0 + 8);
            unsigned e0 = *(const unsigned*)(lb + B0 + RSTRIDE);
            unsigned e1 = *(const unsigned*)(lb + B0 + RSTRIDE + 4);
            unsigned e2 = *(const unsigned*)(lb + B0 + RSTRIDE + 8);
            uint4 bf;
            bf.x = par ? d0 : ((d0 >> 16) | (d1 << 16));
            bf.y = par ? d1 : ((d1 >> 16) | (d2 << 16));
            bf.z = par ? e0 : ((e0 >> 16) | (e1 << 16));
            bf.w = par ? e1 : ((e1 >> 16) | (e2 << 16));
            union { uint4 u; half8 h; } ua, ub;
            ua.u = aw; ub.u = bf;
            acc = __builtin_amdgcn_mfma_f32_32x32x16_f16(ua.h, ub.h, acc, 0, 0, 0);
        }

        // ---- wait for neighbors' h^t rows (producers of y-1, y+1) ----
        if (t > 0 && tx < 2) {
            int ny = tx ? y + 1 : y - 1;
            if ((unsigned)ny < 64u) {
                while (__hip_atomic_load(&prog[b * 64 + ny], __ATOMIC_ACQUIRE,
                                         __HIP_MEMORY_SCOPE_AGENT) < t) { }
            }
        }
        __syncthreads();
        __threadfence();   // invalidate stale cached h lines (cross-XCD safe)

        // ---- stage h rows: cin 16..47 -> LDS rows 48..143 (1536 tasks) ----
        #pragma unroll
        for (int i = 0; i < 6; ++i) {
            int task = i * 256 + tx;
            int rr   = 48 + (task >> 4);     // 48..143
            int qd   = task & 15;
            int cin  = rr / 3;               // 16..47
            int ky   = rr - cin * 3;
            int ys   = y + ky - 1;
            float4 v = make_float4(0.f, 0.f, 0.f, 0.f);
            if ((unsigned)ys < 64u)
                v = *(const float4*)(hsrc + (size_t)(b * 32 + (cin - 16)) * 4096
                                          + ys * 64 + qd * 4);
            plds[rr * 34 + 2 * qd + 1] = pack2(v.x, v.y);
            plds[rr * 34 + 2 * qd + 2] = pack2(v.z, v.w);
        }
        __syncthreads();

        // ---- h GEMM chunks ----
        #pragma unroll
        for (int c = 12; c < 36; ++c) {
            uint4 aw = wfrag[(size_t)((mtile * 36 + c) * 64 + lane)];
            const int B0 = c * 4 * RSTRIDE;
            unsigned d0 = *(const unsigned*)(lb + B0);
            unsigned d1 = *(const unsigned*)(lb + B0 + 4);
            unsigned d2 = *(const unsigned*)(lb + B0 + 8);
            unsigned e0 = *(const unsigned*)(lb + B0 + RSTRIDE);
            unsigned e1 = *(const unsigned*)(lb + B0 + RSTRIDE + 4);
            unsigned e2 = *(const unsigned*)(lb + B0 + RSTRIDE + 8);
            uint4 bf;
            bf.x = par ? d0 : ((d0 >> 16) | (d1 << 16));
            bf.y = par ? d1 : ((d1 >> 16) | (d2 << 16));
            bf.z = par ? e0 : ((e0 >> 16) | (e1 << 16));
            bf.w = par ? e1 : ((e1 >> 16) | (e2 << 16));
            union { uint4 u; half8 h; } ua, ub;
            ua.u = aw; ub.u = bf;
            acc = __builtin_amdgcn_mfma_f32_32x32x16_f16(ua.h, ub.h, acc, 0, 0, 0);
        }

        // ---- epilogue: C rows r (z) / r+16 (n) = regs r / r+8, same lane ----
        #pragma unroll
        for (int r = 0; r < 8; ++r) {
            const int row = (r & 3) + 8 * (r >> 2) + 4 * half;   // 0..15
            const int oc  = mtile * 16 + row;
            const size_t a = (size_t)(b * 32 + oc) * 4096 + y * 64 + xpx;
            float zp = acc[r]     + bx[oc];
            float np = acc[r + 8] + bx[64 + oc];
            float hp = hsrc[a];
            float z  = 1.0f / (1.0f + __expf(-zp));
            float e  = __expf(2.0f * np);
            float n  = 1.0f - 2.0f / (e + 1.0f);                 // tanh
            hdst[a] = (1.0f - z) * hp + z * n;
        }

        __syncthreads();   // barrier drains vmcnt: all waves' h stores complete
        if (tx == 0) {
            __threadfence();                 // write back L2 (cross-XCD visible)
            __hip_atomic_store(&prog[b * 64 + y], t + 1, __ATOMIC_RELEASE,
                               __HIP_MEMORY_SCOPE_AGENT);
        }
        // no barrier needed here: next iteration's staging only overwrites LDS
        // regions all waves finished reading (they passed the barrier above)
    }
}

extern "C" void kernel_launch(void* const* d_in, const int* in_sizes, int n_in,
                              void* d_out, int out_size, void* d_ws, size_t ws_size,
                              hipStream_t stream) {
    const float* x  = (const float*)d_in[0];
    const float* Wx = (const float*)d_in[1];
    const float* bx = (const float*)d_in[2];
    const float* Wh = (const float*)d_in[3];
    float* hA = (float*)d_out;                               // 2 MB h ping
    float* hB = (float*)d_ws;                                // 2 MB h pong
    uint4* wfrag = (uint4*)((char*)d_ws + (4u << 20));       // 74 KB A-frags
    int*   prog  = (int*)((char*)d_ws + (4u << 20) + (256u << 10));  // 4*64 ints

    // h0 = zeros in d_out. prog stays poisoned (negative as signed) -> safe.
    hipMemsetAsync(d_out, 0, (size_t)524288 * sizeof(float), stream);
    hipLaunchKernelGGL(build_wfrag, dim3(72), dim3(64), 0, stream, Wx, Wh, wfrag);

    void* args[] = { (void*)&x, (void*)&bx, (void*)&wfrag,
                     (void*)&hA, (void*)&hB, (void*)&prog };
    hipLaunchCooperativeKernel((const void*)convgru_persist,
                               dim3(64, 4), dim3(256), args, 0, stream);
}

// Round 9
// 641.881 us; speedup vs baseline: 4.8322x; 4.8322x over previous
//
#include <hip/hip_runtime.h>
#include <math.h>

// ConvGRU v8: MFMA implicit-GEMM per timestep (R6 structure), plus:
//  - parity-split LDS copies -> every B-frag dword is an aligned ds_read_b32
//    with immediate offset (no alignbit/cndmask repack VALU)
//  - K-split x2 across 8 waves (512-thr block) -> 2 waves/SIMD latency hiding,
//    combined via LDS reduction
// x: (4,16,64,64,64) f32, Wx: (96,16,3,3), bx: (96), Wh: (96,32,3,3).
// r-gate dead -> M = 32 oc x 2 gates; K = 48 cin x 12 (9 taps + 3 phantoms)
// = 576 = 36 chunks of 16. Staged k-row rr = cin*3+ky (144 rows).
// copy0 row: col c at byte rr*144 + 2*(c+4)   (pairs (even,odd) cols; odd-x lanes)
// copy1 row: dword j = cols (2j-1,2j) at byte CP1 + rr*144 + 4j (even-x lanes)
// h ping-pongs d_out <-> d_ws; t=63 (odd) writes d_out.

typedef _Float16 half8 __attribute__((ext_vector_type(8)));
typedef float floatx16 __attribute__((ext_vector_type(16)));

#define RS 144                       // bytes per staged k-row (both copies)
#define CP1 (144 * RS)               // copy1 byte base (20736)
#define SCRDW (2 * 144 * RS / 4)     // scratch dword base (10368)
#define LDS_DW (SCRDW + 4 * 16 * 68) // + 4 tiles x 16 regs x 68-stride (14720 dw)

static __device__ __forceinline__ unsigned pack2(float a, float b) {
    _Float16 ha = (_Float16)a, hb = (_Float16)b;
    unsigned short ua = *(unsigned short*)&ha, ub = *(unsigned short*)&hb;
    return (unsigned)ua | ((unsigned)ub << 16);
}

// ---- pre-kernel: weights -> A-fragment layout (R6-verified) ----
__global__ __launch_bounds__(64) void build_wfrag(
    const float* __restrict__ Wx, const float* __restrict__ Wh,
    uint4* __restrict__ wfrag)
{
    const int bid   = blockIdx.x;            // 0..71
    const int mtile = bid / 36, chunk = bid % 36;
    const int lane  = threadIdx.x;
    const int m     = lane & 31;
    const int grow  = (m < 16) ? (mtile * 16 + m) : (64 + mtile * 16 + (m - 16));
    unsigned short h[8];
    for (int j = 0; j < 8; ++j) {
        int k   = chunk * 16 + (lane >> 5) * 8 + j;
        int cin = k / 12, t12 = k - cin * 12;
        int p = t12 >> 1, o = t12 & 1;
        int ky = p >> 1, q = p & 1;
        int kx = q ? (2 + o) : o;            // q=1,o=1 -> phantom (w=0)
        float w = 0.0f;
        if (!(q && o)) {
            if (cin < 16) w = Wx[((size_t)grow * 16 + cin) * 9 + ky * 3 + kx];
            else          w = Wh[((size_t)grow * 32 + (cin - 16)) * 9 + ky * 3 + kx];
        }
        _Float16 hw = (_Float16)w;
        h[j] = *(unsigned short*)&hw;
    }
    uint4 o4;
    o4.x = (unsigned)h[0] | ((unsigned)h[1] << 16);
    o4.y = (unsigned)h[2] | ((unsigned)h[3] << 16);
    o4.z = (unsigned)h[4] | ((unsigned)h[5] << 16);
    o4.w = (unsigned)h[6] | ((unsigned)h[7] << 16);
    wfrag[(size_t)bid * 64 + lane] = o4;
}

__global__ __launch_bounds__(512, 1) void convgru_step(
    const float* __restrict__ x, const float* __restrict__ bx,
    const uint4* __restrict__ wfrag,
    const float* __restrict__ hsrc, float* __restrict__ hdst, int t)
{
    __shared__ unsigned plds[LDS_DW];
    const int tx = threadIdx.x;
    const int y  = blockIdx.x;               // image row 0..63
    const int b  = blockIdx.y;               // batch 0..3

    // copy0 right-halo dword (cols 64,65) = 0; staging never writes it
    if (tx < 144) plds[tx * 36 + 34] = 0u;

    // ---- stage 144 k-rows x 16 granules into both parity copies ----
    #pragma unroll
    for (int i = 0; i < 5; ++i) {
        int task = i * 512 + tx;
        if (task < 2304) {
            int rr  = task >> 4;             // 0..143 = cin*3 + ky
            int g   = task & 15;             // granule: cols 4g..4g+3
            int cin = rr / 3;
            int ky  = rr - cin * 3;
            int ys  = y + ky - 1;
            float4 v = make_float4(0.f, 0.f, 0.f, 0.f);
            if ((unsigned)ys < 64u) {
                const float* src = (cin < 16)
                    ? x + (((size_t)(b * 16 + cin) * 64 + t) * 4096)
                    : hsrc + ((size_t)(b * 32 + (cin - 16)) * 4096);
                v = *(const float4*)(src + ys * 64 + g * 4);
            }
            float prev = __shfl_up(v.w, 1);
            if (g == 0) prev = 0.0f;         // col -1 = halo
            const int r36 = rr * 36;
            // copy0: cols (4g,4g+1),(4g+2,4g+3) at dwords r36 + 2g+2, +3
            plds[r36 + 2 * g + 2] = pack2(v.x, v.y);
            plds[r36 + 2 * g + 3] = pack2(v.z, v.w);
            // copy1: cols (4g-1,4g),(4g+1,4g+2) at CP1/4 + r36 + 2g, +1
            plds[CP1 / 4 + r36 + 2 * g]     = pack2(prev, v.x);
            plds[CP1 / 4 + r36 + 2 * g + 1] = pack2(v.y, v.z);
            if (g == 15)                     // copy1 dword 32 = cols (63, 64=halo)
                plds[CP1 / 4 + r36 + 32] = pack2(v.w, 0.0f);
        }
    }
    __syncthreads();

    // ---- wave roles: 8 waves = 2 mtile x 2 ntile x 2 k-halves ----
    const int lane  = tx & 63;
    const int wv    = tx >> 6;               // 0..7
    const int kh    = wv & 1;                // k-half: chunks 0-17 / 18-35
    const int mtile = (wv >> 1) & 1;
    const int ntile = wv >> 2;
    const int tile  = wv >> 1;               // 0..3 (shared by kh pair)
    const int xpx   = ntile * 32 + (lane & 31);
    const int half  = lane >> 5;
    // parity-selected copy: odd x -> copy0 (pairs (x-1,x) start even col);
    // even x -> copy1 (pairs start odd col). All reads dword-aligned.
    const int lb_off = ((xpx & 1) ? (2 * xpx + 6) : (CP1 + 2 * xpx))
                       + half * (2 * RS);
    const char* lbase = (const char*)plds + lb_off;

    // hprev for the epilogue waves (loaded early, L2-hot)
    float hprev[8];
    if (kh == 0) {
        #pragma unroll
        for (int r = 0; r < 8; ++r) {
            const int row = (r & 3) + 8 * (r >> 2) + 4 * half;
            const int oc  = mtile * 16 + row;
            hprev[r] = hsrc[(size_t)(b * 32 + oc) * 4096 + y * 64 + xpx];
        }
    }

    floatx16 acc;
    #pragma unroll
    for (int i = 0; i < 16; ++i) acc[i] = 0.0f;

    const int c0 = kh * 18;
    #pragma unroll
    for (int j = 0; j < 18; ++j) {
        const int c = c0 + j;
        uint4 aw = wfrag[(size_t)((mtile * 36 + c) * 64 + lane)];
        const int B0 = c * 4 * RS;           // chunk's first k-row byte offset
        unsigned d0 = *(const unsigned*)(lbase + B0);        // pairs row R0
        unsigned d1 = *(const unsigned*)(lbase + B0 + 4);
        unsigned e0 = *(const unsigned*)(lbase + B0 + RS);   // pairs row R0+1
        unsigned e1 = *(const unsigned*)(lbase + B0 + RS + 4);
        uint4 bf; bf.x = d0; bf.y = d1; bf.z = e0; bf.w = e1;
        union { uint4 u; half8 h; } ua, ub;
        ua.u = aw; ub.u = bf;
        acc = __builtin_amdgcn_mfma_f32_32x32x16_f16(ua.h, ub.h, acc, 0, 0, 0);
    }

    // ---- K-split reduction: kh=1 waves park accs in LDS scratch ----
    if (kh == 1) {
        #pragma unroll
        for (int r = 0; r < 16; ++r)
            plds[SCRDW + tile * 1088 + r * 68 + lane] = __float_as_uint(acc[r]);
    }
    __syncthreads();

    if (kh == 0) {
        #pragma unroll
        for (int r = 0; r < 16; ++r)
            acc[r] += __uint_as_float(plds[SCRDW + tile * 1088 + r * 68 + lane]);

        // ---- epilogue: C rows r (z) / r+16 (n) = regs r / r+8, same lane ----
        #pragma unroll
        for (int r = 0; r < 8; ++r) {
            const int row = (r & 3) + 8 * (r >> 2) + 4 * half;   // 0..15
            const int oc  = mtile * 16 + row;
            const size_t a = (size_t)(b * 32 + oc) * 4096 + y * 64 + xpx;
            float zp = acc[r]     + bx[oc];
            float np = acc[r + 8] + bx[64 + oc];
            float z  = 1.0f / (1.0f + __expf(-zp));
            float e  = __expf(2.0f * np);
            float n  = 1.0f - 2.0f / (e + 1.0f);                 // tanh
            hdst[a] = (1.0f - z) * hprev[r] + z * n;
        }
    }
}

extern "C" void kernel_launch(void* const* d_in, const int* in_sizes, int n_in,
                              void* d_out, int out_size, void* d_ws, size_t ws_size,
                              hipStream_t stream) {
    const float* x  = (const float*)d_in[0];
    const float* Wx = (const float*)d_in[1];
    const float* bx = (const float*)d_in[2];
    const float* Wh = (const float*)d_in[3];
    float* out = (float*)d_out;
    float* hws = (float*)d_ws;                               // 2 MB h pong
    uint4* wfrag = (uint4*)((char*)d_ws + (4u << 20));       // 74 KB A-frags

    // h0 = zeros in d_out (even t: read out -> write ws; odd t: read ws -> out;
    // t=63 odd => final h lands in d_out).
    hipMemsetAsync(d_out, 0, (size_t)524288 * sizeof(float), stream);
    hipLaunchKernelGGL(build_wfrag, dim3(72), dim3(64), 0, stream, Wx, Wh, wfrag);

    dim3 grid(64, 4), block(512);
    for (int t = 0; t < 64; ++t) {
        const float* src = (t & 1) ? hws : out;
        float*       dst = (t & 1) ? out : hws;
        hipLaunchKernelGGL(convgru_step, grid, block, 0, stream,
                           x, bx, wfrag, src, dst, t);
    }
}